// Round 1
// baseline (365.461 us; speedup 1.0000x reference)
//
#include <hip/hip_runtime.h>
#include <hip/hip_bf16.h>
#include <stdint.h>

#define N_NODES 50000
#define MPAD    50048          // 782 * 64
#define IN_DIM  256
#define EDGES   800000
#define EPRIME  (EDGES + N_NODES)
#define NGRAPH  64
#define GN_EPS  1e-5f
#define ECPAD   53248          // 208 * 256, >= N_NODES
#define NBLK    208

typedef __attribute__((ext_vector_type(8))) short short8;
typedef __attribute__((ext_vector_type(4))) float floatx4;
typedef __attribute__((ext_vector_type(2))) float float2v;

__device__ __forceinline__ uint32_t pk2bf(float a, float b) {
    union { __hip_bfloat162 h; uint32_t u; } cv;
    cv.h = __float22bfloat162_rn(make_float2(a, b));
    return cv.u;
}

__device__ __forceinline__ unsigned short f2b(float f) {
    uint32_t u = __float_as_uint(f);
    u += 0x7fffu + ((u >> 16) & 1u);   // RTNE
    return (unsigned short)(u >> 16);
}

__device__ __forceinline__ float2v up2(uint32_t u) {
    float2v r;
    r[0] = __uint_as_float(u << 16);
    r[1] = __uint_as_float(u & 0xffff0000u);
    return r;
}

// ---------- build Wt[n][k] = W[k][n] bf16, n<256 -> W_l, else W_r ----------
__global__ __launch_bounds__(256) void k_prep_w(const float* __restrict__ Wl,
                                                const float* __restrict__ Wr,
                                                unsigned short* __restrict__ Wt) {
    int idx = blockIdx.x * 256 + threadIdx.x;     // 512*256
    int n = idx >> 8, k = idx & 255;
    float v = (n < 256) ? Wl[k * 256 + n] : Wr[k * 256 + (n - 256)];
    Wt[idx] = f2b(v);
}

// ---------- GEMM: [XL|XR] = bf16(x) @ [W_l|W_r] ----------
__global__ __launch_bounds__(512) void k_gemm(const float* __restrict__ x,
                                              const unsigned short* __restrict__ Wt,
                                              const float* __restrict__ bl,
                                              const float* __restrict__ br,
                                              unsigned short* __restrict__ XL,
                                              unsigned short* __restrict__ XR) {
    __shared__ unsigned short As[64 * 256];       // 32 KB
    int rbase = blockIdx.x * 64;
    int tid = threadIdx.x;

#pragma unroll
    for (int it = 0; it < 4; ++it) {
        int c = it * 512 + tid;
        int row = c >> 5, ch = c & 31;
        int gr = rbase + row;
        float4 f0, f1;
        if (gr < N_NODES) {
            const float4* src = (const float4*)(x + (size_t)gr * 256 + ch * 8);
            f0 = src[0]; f1 = src[1];
        } else {
            f0 = make_float4(0.f,0.f,0.f,0.f); f1 = f0;
        }
        uint32_t p0 = pk2bf(f0.x, f0.y), p1 = pk2bf(f0.z, f0.w);
        uint32_t p2 = pk2bf(f1.x, f1.y), p3 = pk2bf(f1.z, f1.w);
        uint4 hv = make_uint4(p0, p1, p2, p3);
        *(uint4*)(As + row * 256 + (ch ^ (row & 7)) * 8) = hv;
    }
    __syncthreads();

    int w = tid >> 6;
    int l = tid & 63;
    int m = l & 15, q = l >> 4;

    floatx4 acc[4][4];
#pragma unroll
    for (int rf = 0; rf < 4; ++rf)
#pragma unroll
        for (int cf = 0; cf < 4; ++cf)
            acc[rf][cf] = (floatx4){0.f, 0.f, 0.f, 0.f};

    const unsigned short* wbase = Wt + (size_t)(w * 64) * 256;

#pragma unroll
    for (int kk = 0; kk < 8; ++kk) {
        short8 a[4];
#pragma unroll
        for (int rf = 0; rf < 4; ++rf) {
            int row = rf * 16 + m;
            int ch = (kk * 4 + q) ^ (row & 7);
            a[rf] = *(const short8*)(As + row * 256 + ch * 8);
        }
#pragma unroll
        for (int cf = 0; cf < 4; ++cf) {
            short8 b = *(const short8*)(wbase + (size_t)(cf * 16 + m) * 256 + kk * 32 + q * 8);
#pragma unroll
            for (int rf = 0; rf < 4; ++rf)   // A-slot = W frag -> D = C^T tile
                acc[rf][cf] = __builtin_amdgcn_mfma_f32_16x16x32_bf16(b, a[rf], acc[rf][cf], 0, 0, 0);
        }
    }

    // D layout (transposed compute): node = lane&15, channel = q*4 + reg.
    unsigned short* obase = (w < 4) ? XL : XR;
    const float* bptr = (w < 4) ? bl : br;
    int cb = (w & 3) * 64;
#pragma unroll
    for (int cf = 0; cf < 4; ++cf) {
        int chb = cb + cf * 16 + q * 4;
        float4 bv = *(const float4*)(bptr + chb);
#pragma unroll
        for (int rf = 0; rf < 4; ++rf) {
            int node = rbase + rf * 16 + m;
            uint2 o;
            o.x = pk2bf(acc[rf][cf][0] + bv.x, acc[rf][cf][1] + bv.y);
            o.y = pk2bf(acc[rf][cf][2] + bv.z, acc[rf][cf][3] + bv.w);
            *(uint2*)(obase + (size_t)node * 256 + chb) = o;  // pad rows exist
        }
    }
}

// ---------- fused histograms + sedge tail pad ----------
__global__ __launch_bounds__(256) void k_hist(const int* __restrict__ ei,
                                              const int* __restrict__ batch,
                                              int* __restrict__ ecount,
                                              int* __restrict__ ncount,
                                              int* __restrict__ sedge) {
    __shared__ int hist[NGRAPH];
    if (threadIdx.x < NGRAPH) hist[threadIdx.x] = 0;
    __syncthreads();
    int e = blockIdx.x * 256 + threadIdx.x;
    if (e < EPRIME) {
        int d = (e < EDGES) ? ei[EDGES + e] : (e - EDGES);
        atomicAdd(&ecount[d], 1);
    }
    if (e < N_NODES) atomicAdd(&hist[batch[e]], 1);
    if (blockIdx.x == 0 && threadIdx.x < 192) sedge[EPRIME + threadIdx.x] = 0;
    __syncthreads();
    if (threadIdx.x < NGRAPH && hist[threadIdx.x])
        atomicAdd(&ncount[threadIdx.x], hist[threadIdx.x]);
}

// ---------- 3-phase device-wide exclusive scan of ecount ----------
__global__ __launch_bounds__(256) void k_scan1(const int* __restrict__ ecount,
                                               int* __restrict__ bsum) {
    __shared__ int red[256];
    int v = ecount[blockIdx.x * 256 + threadIdx.x];
    red[threadIdx.x] = v;
    __syncthreads();
    for (int off = 128; off > 0; off >>= 1) {
        if (threadIdx.x < off) red[threadIdx.x] += red[threadIdx.x + off];
        __syncthreads();
    }
    if (threadIdx.x == 0) bsum[blockIdx.x] = red[0];
}

__global__ __launch_bounds__(256) void k_scan2(int* __restrict__ bsum) {
    __shared__ int buf[256];
    int t = threadIdx.x;
    int v = (t < NBLK) ? bsum[t] : 0;
    buf[t] = v;
    __syncthreads();
    for (int off = 1; off < 256; off <<= 1) {
        int p = (t >= off) ? buf[t - off] : 0;
        __syncthreads();
        buf[t] += p;
        __syncthreads();
    }
    if (t < NBLK) bsum[t] = buf[t] - v;      // exclusive
}

__global__ __launch_bounds__(256) void k_scan3(const int* __restrict__ ecount,
                                               const int* __restrict__ bsum,
                                               int* __restrict__ estart,
                                               int* __restrict__ ecursor) {
    __shared__ int buf[256];
    int b = blockIdx.x, t = threadIdx.x;
    int v = ecount[b * 256 + t];
    buf[t] = v;
    __syncthreads();
    for (int off = 1; off < 256; off <<= 1) {
        int p = (t >= off) ? buf[t - off] : 0;
        __syncthreads();
        buf[t] += p;
        __syncthreads();
    }
    int e = bsum[b] + buf[t] - v;
    estart[b * 256 + t]  = e;
    ecursor[b * 256 + t] = e;
}

// ---------- scatter edges into dst-sorted order (store src only) ----------
__global__ __launch_bounds__(256) void k_scatter(const int* __restrict__ ei,
                                                 int* __restrict__ ecursor,
                                                 int* __restrict__ sedge) {
    int e = blockIdx.x * 256 + threadIdx.x;
    if (e >= EPRIME) return;
    int s, d;
    if (e < EDGES) { s = ei[e]; d = ei[EDGES + e]; }
    else           { s = d = e - EDGES; }
    int pos = atomicAdd(&ecursor[d], 1);
    sedge[pos] = s;
}

// ---------- core v2: one wave per dst, TWO edges per wave pass ----------
// lanes 0-31 = edge-stream A, lanes 32-63 = edge-stream B; 8 channels/lane
// via one uint4 (dwordx4). Head = (l&31)>>2 spans 4 lanes -> 2-DPP reduce,
// no ds_swizzle. All sedge indices for a dst staged into 2 VGPRs up front
// (v_readlane thereafter) -> no per-edge dependent sedge load. Row prefetch
// stays 4 pairs = 8 edges deep.
__global__ __launch_bounds__(256) void k_msg(const unsigned short* __restrict__ XL,
                                             const unsigned short* __restrict__ XRb,
                                             const float* __restrict__ x,
                                             const float* __restrict__ att,
                                             const float* __restrict__ bias,
                                             const int* __restrict__ sedge,
                                             const int* __restrict__ estart,
                                             const int* __restrict__ ecount,
                                             float* __restrict__ out) {
    int d = (int)((blockIdx.x * 256 + threadIdx.x) >> 6);
    int l = threadIdx.x & 63;
    int j = l & 31;                    // slice id within half: ch in [8j, 8j+8)
    int half = l >> 5;                 // 0 = stream A, 1 = stream B
    uint32_t jofs = (uint32_t)j * 16u; // byte offset of this lane's uint4 in a row
    float hmask = (half == 0) ? 1.f : 0.f;

    // per-dst operands for this lane's 8 channels
    uint4 xr4 = ((const uint4*)(XRb + (size_t)d * 256))[j];
    float2v xr01 = up2(xr4.x), xr23 = up2(xr4.y), xr45 = up2(xr4.z), xr67 = up2(xr4.w);
    float4 at0 = ((const float4*)att)[j * 2];
    float4 at1 = ((const float4*)att)[j * 2 + 1];
    float2v a01 = {at0.x, at0.y}, a23 = {at0.z, at0.w};
    float2v a45 = {at1.x, at1.y}, a67 = {at1.z, at1.w};

    int s0  = __builtin_amdgcn_readfirstlane(estart[d]);
    int cnt = __builtin_amdgcn_readfirstlane(ecount[d]);

    // stage all src indices into registers (sedge has 192-zero tail pad)
    int esrc0 = sedge[s0 + l];
    int esrc1 = sedge[s0 + 64 + l];

    int hA = (cnt + 1) >> 1;           // A-stream edges [0, hA)
    int nB = cnt >> 1;                 // B-stream edges [hA, hA+nB)

    auto getsrc = [&](int i) -> int {  // i is wave-uniform
        if (i < 128) {
            int lo = __builtin_amdgcn_readlane(esrc0, i & 63);
            int hi = __builtin_amdgcn_readlane(esrc1, i & 63);
            return (i < 64) ? lo : hi;
        }
        return sedge[s0 + i];          // effectively never (cnt > 120)
    };
    auto ldpair = [&](int sA, int sB) -> uint4 {
        uint32_t s = half ? (uint32_t)sB : (uint32_t)sA;
        return *(const uint4*)((const char*)XL + (((size_t)s) << 9) + jofs);
    };

    float den0 = 0.f, den1 = 0.f;
    float2v A01={0.f,0.f}, A23={0.f,0.f}, A45={0.f,0.f}, A67={0.f,0.f};
    float2v B01={0.f,0.f}, B23={0.f,0.f}, B45={0.f,0.f}, B67={0.f,0.f};

    auto proc = [&](uint4 U, float hm, float& den, float2v& R01, float2v& R23,
                    float2v& R45, float2v& R67) {
        float2v x01 = up2(U.x), x23 = up2(U.y), x45 = up2(U.z), x67 = up2(U.w);
        float2v z01 = x01 + xr01, z23 = x23 + xr23;
        float2v z45 = x45 + xr45, z67 = x67 + xr67;
        float2v f01 = z01 * 0.2f, f23 = z23 * 0.2f;
        float2v f45 = z45 * 0.2f, f67 = z67 * 0.2f;
        z01[0] = fmaxf(z01[0], f01[0]); z01[1] = fmaxf(z01[1], f01[1]);
        z23[0] = fmaxf(z23[0], f23[0]); z23[1] = fmaxf(z23[1], f23[1]);
        z45[0] = fmaxf(z45[0], f45[0]); z45[1] = fmaxf(z45[1], f45[1]);
        z67[0] = fmaxf(z67[0], f67[0]); z67[1] = fmaxf(z67[1], f67[1]);
        float2v pp2 = z01 * a01;
        pp2 += z23 * a23;
        pp2 += z45 * a45;
        pp2 += z67 * a67;
        float pp = pp2[0] + pp2[1];
        // 4-lane head reduce: xor1, xor2 via DPP quad_perm (head = 4 lanes now)
        int pi = __float_as_int(pp);
        pp += __int_as_float(__builtin_amdgcn_update_dpp(0, pi, 0xB1, 0xF, 0xF, true));
        pi = __float_as_int(pp);
        pp += __int_as_float(__builtin_amdgcn_update_dpp(0, pi, 0x4E, 0xF, 0xF, true));
        float al = __expf(fminf(pp, 80.f)) * hm;
        den += al;
        float2v al2 = {al, al};
        R01 += al2 * x01; R23 += al2 * x23;
        R45 += al2 * x45; R67 += al2 * x67;
    };

    // prefetch pairs 0..3 (overshoot reads hit next dst's edges or zero pad)
    uint4 P0 = ldpair(getsrc(0), getsrc(hA));
    uint4 P1 = ldpair(getsrc(1), getsrc(hA + 1));
    uint4 P2 = ldpair(getsrc(2), getsrc(hA + 2));
    uint4 P3 = ldpair(getsrc(3), getsrc(hA + 3));

    int nq = nB >> 2, rem = nB & 3;
    for (int qq = 0; qq < nq; ++qq) {
        uint4 Q0 = P0, Q1 = P1, Q2 = P2, Q3 = P3;
        int b = (qq + 1) * 4;
        P0 = ldpair(getsrc(b),     getsrc(hA + b));
        P1 = ldpair(getsrc(b + 1), getsrc(hA + b + 1));
        P2 = ldpair(getsrc(b + 2), getsrc(hA + b + 2));
        P3 = ldpair(getsrc(b + 3), getsrc(hA + b + 3));
        proc(Q0, 1.f, den0, A01, A23, A45, A67);
        proc(Q1, 1.f, den1, B01, B23, B45, B67);
        proc(Q2, 1.f, den0, A01, A23, A45, A67);
        proc(Q3, 1.f, den1, B01, B23, B45, B67);
    }
    if (rem > 0) proc(P0, 1.f, den0, A01, A23, A45, A67);
    if (rem > 1) proc(P1, 1.f, den1, B01, B23, B45, B67);
    if (rem > 2) proc(P2, 1.f, den0, A01, A23, A45, A67);
    if (cnt & 1) {
        // lone A edge = pair index nB, already resident in P[rem]; B half masked
        if      (rem == 0) proc(P0, hmask, den1, B01, B23, B45, B67);
        else if (rem == 1) proc(P1, hmask, den1, B01, B23, B45, B67);
        else if (rem == 2) proc(P2, hmask, den1, B01, B23, B45, B67);
        else               proc(P3, hmask, den1, B01, B23, B45, B67);
    }

    // combine streams, then cross-half (A-lanes <-> B-lanes) combine
    float den = den0 + den1;
    den += __shfl_xor(den, 32);
    float2v R01 = A01 + B01, R23 = A23 + B23, R45 = A45 + B45, R67 = A67 + B67;
    R01[0] += __shfl_xor(R01[0], 32); R01[1] += __shfl_xor(R01[1], 32);
    R23[0] += __shfl_xor(R23[0], 32); R23[1] += __shfl_xor(R23[1], 32);
    R45[0] += __shfl_xor(R45[0], 32); R45[1] += __shfl_xor(R45[1], 32);
    R67[0] += __shfl_xor(R67[0], 32); R67[1] += __shfl_xor(R67[1], 32);
    float inv = 1.f / (den + 1e-16f);

    // half 0 writes ch [8j, 8j+4), half 1 writes ch [8j+4, 8j+8): full row
    bool hi = (half != 0);
    float c0 = hi ? R45[0] : R01[0];
    float c1 = hi ? R45[1] : R01[1];
    float c2 = hi ? R67[0] : R23[0];
    float c3 = hi ? R67[1] : R23[1];
    int chb = j * 8 + half * 4;
    float4 xin = *(const float4*)(x + (size_t)d * 256 + chb);
    float4 bv  = *(const float4*)(bias + chb);
    float h0 = c0 * inv + bv.x + xin.x; h0 = (h0 > 0.f) ? h0 : (__expf(h0) - 1.f);
    float h1 = c1 * inv + bv.y + xin.y; h1 = (h1 > 0.f) ? h1 : (__expf(h1) - 1.f);
    float h2 = c2 * inv + bv.z + xin.z; h2 = (h2 > 0.f) ? h2 : (__expf(h2) - 1.f);
    float h3 = c3 * inv + bv.w + xin.w; h3 = (h3 > 0.f) ? h3 : (__expf(h3) - 1.f);
    *(float4*)(out + (size_t)d * 256 + chb) = make_float4(h0, h1, h2, h3);
}

// ---------- GraphNorm stats: 64-row blocks, 4-row unrolled fast path ----------
#define GN_ROWS 64
__global__ __launch_bounds__(256) void k_gn_sum(const float* __restrict__ h,
                                                const int* __restrict__ batch,
                                                float* __restrict__ gsum,
                                                float* __restrict__ gsq) {
    __shared__ int bsh[GN_ROWS];
    int r0 = blockIdx.x * GN_ROWS;
    if (threadIdx.x < GN_ROWS) {
        int i = r0 + threadIdx.x;
        bsh[threadIdx.x] = (i < N_NODES) ? batch[i] : -1;
    }
    __syncthreads();
    int c = threadIdx.x;
    float s1 = 0.f, s2 = 0.f;
    int g = bsh[0];
    for (int j = 0; j < GN_ROWS; j += 4) {
        int i = r0 + j;
        if (i >= N_NODES) break;
        bool full = (i + 3 < N_NODES);
        if (full && bsh[j] == g && bsh[j + 3] == g) {
            const float* hp = h + (size_t)i * 256 + c;
            float v0 = hp[0], v1 = hp[256], v2 = hp[512], v3 = hp[768];
            s1 += (v0 + v1) + (v2 + v3);
            s2 += (v0 * v0 + v1 * v1) + (v2 * v2 + v3 * v3);
        } else {
            for (int jj = j; jj < j + 4; ++jj) {
                int ii = r0 + jj;
                if (ii >= N_NODES) break;
                int bg = bsh[jj];
                if (bg != g) {
                    atomicAdd(&gsum[g * 256 + c], s1);
                    atomicAdd(&gsq[g * 256 + c], s2);
                    s1 = 0.f; s2 = 0.f; g = bg;
                }
                float v = h[(size_t)ii * 256 + c];
                s1 += v; s2 += v * v;
            }
        }
    }
    atomicAdd(&gsum[g * 256 + c], s1);
    atomicAdd(&gsq[g * 256 + c], s2);
}

// ---------- GraphNorm finalize: var = E[h^2] - m^2 * s * (2 - s) ----------
__global__ __launch_bounds__(256) void k_final(float* __restrict__ out,
                                               const int* __restrict__ batch,
                                               const float* __restrict__ gsum,
                                               const float* __restrict__ gsq,
                                               const int* __restrict__ ncount,
                                               const float* __restrict__ gnw,
                                               const float* __restrict__ gnb,
                                               const float* __restrict__ gms) {
    int idx = blockIdx.x * 256 + threadIdx.x;
    int i = idx >> 6, l = idx & 63;
    if (i >= N_NODES) return;
    int g = batch[i];
    float inv = 1.f / fmaxf((float)ncount[g], 1.f);
    float4 hv = ((const float4*)(out + (size_t)i * 256))[l];
    float4 ms = ((const float4*)(gsum + g * 256))[l];
    float4 qs = ((const float4*)(gsq  + g * 256))[l];
    float4 wv = ((const float4*)gnw)[l];
    float4 bv = ((const float4*)gnb)[l];
    float4 sv = ((const float4*)gms)[l];
    float4 o;
    {
        float m = ms.x * inv, q = qs.x * inv;
        o.x = wv.x * (hv.x - sv.x * m) * rsqrtf(q - m * m * sv.x * (2.f - sv.x) + GN_EPS) + bv.x;
    }
    {
        float m = ms.y * inv, q = qs.y * inv;
        o.y = wv.y * (hv.y - sv.y * m) * rsqrtf(q - m * m * sv.y * (2.f - sv.y) + GN_EPS) + bv.y;
    }
    {
        float m = ms.z * inv, q = qs.z * inv;
        o.z = wv.z * (hv.z - sv.z * m) * rsqrtf(q - m * m * sv.z * (2.f - sv.z) + GN_EPS) + bv.z;
    }
    {
        float m = ms.w * inv, q = qs.w * inv;
        o.w = wv.w * (hv.w - sv.w * m) * rsqrtf(q - m * m * sv.w * (2.f - sv.w) + GN_EPS) + bv.w;
    }
    ((float4*)(out + (size_t)i * 256))[l] = o;
}

extern "C" void kernel_launch(void* const* d_in, const int* in_sizes, int n_in,
                              void* d_out, int out_size, void* d_ws, size_t ws_size,
                              hipStream_t stream) {
    const float* x    = (const float*)d_in[0];
    const int*   ei   = (const int*)d_in[1];
    const int*   batch= (const int*)d_in[2];
    const float* Wl   = (const float*)d_in[3];
    const float* bl   = (const float*)d_in[4];
    const float* Wr   = (const float*)d_in[5];
    const float* br   = (const float*)d_in[6];
    const float* att  = (const float*)d_in[7];
    const float* bias = (const float*)d_in[8];
    const float* gnw  = (const float*)d_in[9];
    const float* gnb  = (const float*)d_in[10];
    const float* gms  = (const float*)d_in[11];
    float* out = (float*)d_out;

    char* p = (char*)d_ws;
    auto alloc = [&](size_t bytes) -> char* {
        char* r = p;
        p += (bytes + 255) & ~(size_t)255;
        return r;
    };
    unsigned short* Wt  = (unsigned short*)alloc((size_t)512 * 256 * 2);
    unsigned short* XL  = (unsigned short*)alloc((size_t)MPAD * 256 * 2);
    unsigned short* XRb = (unsigned short*)alloc((size_t)MPAD * 256 * 2);
    int* estart         = (int*)alloc((size_t)ECPAD * 4);
    int* ecursor        = (int*)alloc((size_t)ECPAD * 4);
    int* sedge          = (int*)alloc((size_t)(EPRIME + 192) * 4);
    int* bsum           = (int*)alloc((size_t)256 * 4);
    // ---- contiguous zero-init region: ecount | ncount | gsum | gsq ----
    int* ecount         = (int*)alloc((size_t)ECPAD * 4);
    int* ncount         = (int*)alloc((size_t)NGRAPH * 4);
    float* gsum         = (float*)alloc((size_t)2 * NGRAPH * 256 * 4);  // gsum || gsq
    float* gsq          = gsum + NGRAPH * 256;
    size_t zbytes = (size_t)((char*)(gsum + 2 * NGRAPH * 256) - (char*)ecount);
    hipMemsetAsync(ecount, 0, zbytes, stream);

    k_prep_w<<<512, 256, 0, stream>>>(Wl, Wr, Wt);
    k_gemm<<<MPAD / 64, 512, 0, stream>>>(x, Wt, bl, br, XL, XRb);

    k_hist<<<(EPRIME + 255) / 256, 256, 0, stream>>>(ei, batch, ecount, ncount, sedge);
    k_scan1<<<NBLK, 256, 0, stream>>>(ecount, bsum);
    k_scan2<<<1, 256, 0, stream>>>(bsum);
    k_scan3<<<NBLK, 256, 0, stream>>>(ecount, bsum, estart, ecursor);
    k_scatter<<<(EPRIME + 255) / 256, 256, 0, stream>>>(ei, ecursor, sedge);

    k_msg<<<N_NODES / 4, 256, 0, stream>>>(XL, XRb, x, att, bias,
                                           sedge, estart, ecount, out);

    k_gn_sum<<<(N_NODES + GN_ROWS - 1) / GN_ROWS, 256, 0, stream>>>(out, batch, gsum, gsq);
    k_final<<<N_NODES * 64 / 256, 256, 0, stream>>>(out, batch, gsum, gsq,
                                                    ncount, gnw, gnb, gms);
}